// Round 11
// baseline (1186.558 us; speedup 1.0000x reference)
//
#include <hip/hip_runtime.h>
#include <stdint.h>

typedef int v4i __attribute__((ext_vector_type(4)));

#define K_DIM 4096
#define TPB_Q 256
#define BM 256
#define BN 256
#define BKB 64                      // K-bytes per tile
#define NT (K_DIM / BKB)            // 64 K-tiles
#define TILE_BYTES (256 * BKB)      // 16 KiB per operand tile

__device__ __forceinline__ void load_lds16(const void* g, void* l) {
  __builtin_amdgcn_global_load_lds(
      (const __attribute__((address_space(1))) void*)g,
      (__attribute__((address_space(3))) void*)l, 16, 0, 0);
}

// ---------------- per-row symmetric int8 quant (BW-bound, unchanged) --------
__global__ __launch_bounds__(TPB_Q) void quant_rows_kernel(
    const float* __restrict__ x, signed char* __restrict__ q,
    float* __restrict__ scales) {
  const int row = blockIdx.x;
  const float4* xr = (const float4*)(x + (size_t)row * K_DIM);
  float4 v[4];
  float m = 0.0f;
#pragma unroll
  for (int i = 0; i < 4; ++i) {
    v[i] = xr[threadIdx.x + i * TPB_Q];
    m = fmaxf(m, fmaxf(fmaxf(fabsf(v[i].x), fabsf(v[i].y)),
                       fmaxf(fabsf(v[i].z), fabsf(v[i].w))));
  }
#pragma unroll
  for (int off = 32; off > 0; off >>= 1) m = fmaxf(m, __shfl_down(m, off));
  __shared__ float red[TPB_Q / 64];
  if ((threadIdx.x & 63) == 0) red[threadIdx.x >> 6] = m;
  __syncthreads();
  m = fmaxf(fmaxf(red[0], red[1]), fmaxf(red[2], red[3]));
  const float scale = fmaxf(m / 127.0f, 1e-8f);
  if (threadIdx.x == 0) scales[row] = scale;
  uint32_t* qr = (uint32_t*)(q + (size_t)row * K_DIM);
#pragma unroll
  for (int i = 0; i < 4; ++i) {
    const float4 t = v[i];
    const int a0 = (int)fminf(fmaxf(rintf(t.x / scale), -128.0f), 127.0f);
    const int a1 = (int)fminf(fmaxf(rintf(t.y / scale), -128.0f), 127.0f);
    const int a2 = (int)fminf(fmaxf(rintf(t.z / scale), -128.0f), 127.0f);
    const int a3 = (int)fminf(fmaxf(rintf(t.w / scale), -128.0f), 127.0f);
    const uint32_t p = (uint32_t)(a0 & 255) | ((uint32_t)(a1 & 255) << 8) |
                       ((uint32_t)(a2 & 255) << 16) | ((uint32_t)(a3 & 255) << 24);
    qr[threadIdx.x + i * TPB_Q] = p;
  }
}

// ---------------- 256x256 i8 GEMM, BK=64, 2 blocks/CU free-run -------------
// R8's 1-barrier free-run schedule with BK halved so LDS = 64 KiB/block ->
// 2 blocks/CU; cross-block wave overlap absorbs each block's boundary
// drain (the ~40% idle matrix-pipe time at 1 block/CU).
// 8 waves: wm (2) x wn (4); per-wave C 128x64 = acc[8][4] (128 AGPRs);
// fragments a[8]+b[4] = 48 VGPRs (well under the 128-cap, R9 lesson).
// LDS: A,B full-tile double buffers (4 x 16 KiB); rows are 64 B = 4 chunks;
// swizzle phys_chunk = logical ^ ((row>>1)&3) -> fragment reads are 2-way
// bank-aliased (free, m136); staging dest linear, source inverse-swizzled.
// Per K-tile: 12 ds_reads pinned (b4+a01 | a23 | a45 | a67), stage T+1
// (4 gload_lds), MFMA row-pairs gated lgkmcnt(6)/(4)/(2)/(0) (free-run,
// no intra-tile barrier), vmcnt(0)+s_barrier at boundary (stage had the
// full MFMA span to land).
// XCD swizzle: grid 32r x 16c; XCD k owns rows[8*(k>>1),+8) x cols[8*(k&1),+8).
__global__ __launch_bounds__(512, 4) void gemm_i8_kernel(
    const signed char* __restrict__ qA, const signed char* __restrict__ qB,
    const float* __restrict__ sA, const float* __restrict__ sB,
    float* __restrict__ C, int M, int N, int K) {
  __shared__ __align__(16) signed char As[2 * TILE_BYTES];  // 32 KiB
  __shared__ __align__(16) signed char Bs[2 * TILE_BYTES];  // 32 KiB

  const int tid = threadIdx.x;
  const int wave = tid >> 6, lane = tid & 63;
  const int l16 = lane & 15, lhi = lane >> 4;
  const int wm = wave >> 2, wn = wave & 3;

  // XCD-chunked 2-D swizzle (bijective; 512 blocks, 8 XCDs, o%8 = XCD)
  const int o = blockIdx.x + blockIdx.y * gridDim.x;
  const int xcd = o & 7, slot = o >> 3;
  const int rb = ((xcd >> 1) << 3) + (slot >> 3);  // grid row 0..31
  const int cb = ((xcd & 1) << 3) + (slot & 7);    // grid col 0..15
  const int m0 = rb * BM, n0 = cb * BN;

  const signed char* Abase = qA + (size_t)m0 * K;
  const signed char* Bbase = qB + (size_t)n0 * K;

  // staging: tile = 1024 x 16B chunks; thread d = s*512+tid, s=0..1.
  // dest linear (wave-uniform base + lane*16); source inverse-swizzled.
  int soff[2], sdst[2];
#pragma unroll
  for (int s = 0; s < 2; ++s) {
    const int d = s * 512 + tid;
    const int r = d >> 2;                       // row 0..255 (4 chunks/row)
    const int c = (d & 3) ^ ((r >> 1) & 3);     // logical chunk at phys (d&3)
    soff[s] = r * K + c * 16;
    sdst[s] = s * 8192 + wave * 1024;
  }

#define STAGE_A(T_)                                                         \
  do {                                                                      \
    _Pragma("unroll") for (int s = 0; s < 2; ++s)                           \
        load_lds16(Abase + (size_t)(T_)*BKB + soff[s],                      \
                   As + ((T_)&1) * TILE_BYTES + sdst[s]);                   \
  } while (0)
#define STAGE_B(T_)                                                         \
  do {                                                                      \
    _Pragma("unroll") for (int s = 0; s < 2; ++s)                           \
        load_lds16(Bbase + (size_t)(T_)*BKB + soff[s],                      \
                   Bs + ((T_)&1) * TILE_BYTES + sdst[s]);                   \
  } while (0)

  // fragment read offsets: row = (64|128-mult) + l16, k-chunk = lhi (K=64),
  // phys = lhi ^ ((row>>1)&3) = lhi ^ ((l16>>1)&3)
  const int axor = ((lhi ^ ((l16 >> 1) & 3)) << 4);
  const int aoff = wm * 8192 + l16 * 64;  // + mi*1024
  const int boff = wn * 4096 + l16 * 64;  // + nj*1024

  const v4i vz = {0, 0, 0, 0};
  v4i acc[8][4];
#pragma unroll
  for (int i = 0; i < 8; ++i)
#pragma unroll
    for (int j = 0; j < 4; ++j) acc[i][j] = vz;

  // prologue: stage tile 0, drain, sync.
  STAGE_A(0); STAGE_B(0);
  asm volatile("s_waitcnt vmcnt(0)" ::: "memory");
  __builtin_amdgcn_s_barrier();

#define MFMA_PAIR(p0_, p1_)                                                  \
  do {                                                                       \
    _Pragma("unroll") for (int nj = 0; nj < 4; ++nj)                         \
        acc[p0_][nj] = __builtin_amdgcn_mfma_i32_16x16x64_i8(                \
            a[p0_], b[nj], acc[p0_][nj], 0, 0, 0);                           \
    _Pragma("unroll") for (int nj = 0; nj < 4; ++nj)                         \
        acc[p1_][nj] = __builtin_amdgcn_mfma_i32_16x16x64_i8(                \
            a[p1_], b[nj], acc[p1_][nj], 0, 0, 0);                           \
  } while (0)

#define LGKM_GATE(n_)                                       \
  do {                                                      \
    asm volatile("s_waitcnt lgkmcnt(" #n_ ")" ::: "memory");\
    __builtin_amdgcn_sched_barrier(0);                      \
  } while (0)

  for (int T = 0; T < NT; ++T) {
    const signed char* Ar = As + (T & 1) * TILE_BYTES;
    const signed char* Br = Bs + (T & 1) * TILE_BYTES;
    v4i a[8], b[4];

    // pinned read issue: b(4)+a01(2) | a23(2) | a45(2) | a67(2)
#pragma unroll
    for (int nj = 0; nj < 4; ++nj)
      b[nj] = *(const v4i*)(Br + boff + nj * 1024 + axor);
    a[0] = *(const v4i*)(Ar + aoff + 0 * 1024 + axor);
    a[1] = *(const v4i*)(Ar + aoff + 1 * 1024 + axor);
    __builtin_amdgcn_sched_barrier(0);
    a[2] = *(const v4i*)(Ar + aoff + 2 * 1024 + axor);
    a[3] = *(const v4i*)(Ar + aoff + 3 * 1024 + axor);
    __builtin_amdgcn_sched_barrier(0);
    a[4] = *(const v4i*)(Ar + aoff + 4 * 1024 + axor);
    a[5] = *(const v4i*)(Ar + aoff + 5 * 1024 + axor);
    __builtin_amdgcn_sched_barrier(0);
    a[6] = *(const v4i*)(Ar + aoff + 6 * 1024 + axor);
    a[7] = *(const v4i*)(Ar + aoff + 7 * 1024 + axor);
    __builtin_amdgcn_sched_barrier(0);

    // stage next tile into buf^1 (no WAR: reads are from buf)
    if (T + 1 < NT) { STAGE_A(T + 1); STAGE_B(T + 1); }

    // MFMA clusters, counted lgkm gates, free-run (no barriers)
    LGKM_GATE(6);
    __builtin_amdgcn_s_setprio(1);
    MFMA_PAIR(0, 1);
    __builtin_amdgcn_s_setprio(0);
    LGKM_GATE(4);
    __builtin_amdgcn_s_setprio(1);
    MFMA_PAIR(2, 3);
    __builtin_amdgcn_s_setprio(0);
    LGKM_GATE(2);
    __builtin_amdgcn_s_setprio(1);
    MFMA_PAIR(4, 5);
    __builtin_amdgcn_s_setprio(0);
    LGKM_GATE(0);
    __builtin_amdgcn_s_setprio(1);
    MFMA_PAIR(6, 7);
    __builtin_amdgcn_s_setprio(0);

    // boundary: own stage landed (covered by MFMA span), cross-wave fence
    asm volatile("s_waitcnt vmcnt(0)" ::: "memory");
    __builtin_amdgcn_s_barrier();
  }

  // epilogue: C/D layout col = lane&15, row = (lane>>4)*4 + reg
  float sbv[4];
#pragma unroll
  for (int nj = 0; nj < 4; ++nj) sbv[nj] = sB[n0 + wn * 64 + nj * 16 + l16];
#pragma unroll
  for (int mi = 0; mi < 8; ++mi) {
#pragma unroll
    for (int r = 0; r < 4; ++r) {
      const int row = m0 + wm * 128 + mi * 16 + lhi * 4 + r;
      const float sav = sA[row];
      float* crow = C + (size_t)row * N + (n0 + wn * 64 + l16);
#pragma unroll
      for (int nj = 0; nj < 4; ++nj)
        crow[nj * 16] = (float)acc[mi][nj][r] * sav * sbv[nj];
    }
  }
}

extern "C" void kernel_launch(void* const* d_in, const int* in_sizes, int n_in,
                              void* d_out, int out_size, void* d_ws, size_t ws_size,
                              hipStream_t stream) {
  const float* A = (const float*)d_in[0];
  const float* B = (const float*)d_in[1];
  float* C = (float*)d_out;
  const int K = K_DIM;
  const int M = in_sizes[0] / K;  // 8192
  const int N = in_sizes[1] / K;  // 4096

  signed char* qA = (signed char*)d_ws;
  signed char* qB = qA + (size_t)M * K;
  float* sA = (float*)(qB + (size_t)N * K);
  float* sB = sA + M;

  quant_rows_kernel<<<M, TPB_Q, 0, stream>>>(A, qA, sA);
  quant_rows_kernel<<<N, TPB_Q, 0, stream>>>(B, qB, sB);

  dim3 grid(N / BN, M / BM);
  gemm_i8_kernel<<<grid, 512, 0, stream>>>(qA, qB, sA, sB, C, M, N, K);
}

// Round 13
// 207.683 us; speedup vs baseline: 5.7133x; 5.7133x over previous
//
#include <hip/hip_runtime.h>
#include <stdint.h>

typedef int v4i __attribute__((ext_vector_type(4)));

#define K_DIM 4096
#define TPB_Q 256
#define BM 256
#define BN 256
#define BKB 64                      // K-bytes per tile
#define NT (K_DIM / BKB)            // 64 K-tiles
#define TILE_BYTES (256 * BKB)      // 16 KiB per operand tile

__device__ __forceinline__ void load_lds16(const void* g, void* l) {
  __builtin_amdgcn_global_load_lds(
      (const __attribute__((address_space(1))) void*)g,
      (__attribute__((address_space(3))) void*)l, 16, 0, 0);
}

// ---------------- per-row symmetric int8 quant (BW-bound, unchanged) --------
__global__ __launch_bounds__(TPB_Q) void quant_rows_kernel(
    const float* __restrict__ x, signed char* __restrict__ q,
    float* __restrict__ scales) {
  const int row = blockIdx.x;
  const float4* xr = (const float4*)(x + (size_t)row * K_DIM);
  float4 v[4];
  float m = 0.0f;
#pragma unroll
  for (int i = 0; i < 4; ++i) {
    v[i] = xr[threadIdx.x + i * TPB_Q];
    m = fmaxf(m, fmaxf(fmaxf(fabsf(v[i].x), fabsf(v[i].y)),
                       fmaxf(fabsf(v[i].z), fabsf(v[i].w))));
  }
#pragma unroll
  for (int off = 32; off > 0; off >>= 1) m = fmaxf(m, __shfl_down(m, off));
  __shared__ float red[TPB_Q / 64];
  if ((threadIdx.x & 63) == 0) red[threadIdx.x >> 6] = m;
  __syncthreads();
  m = fmaxf(fmaxf(red[0], red[1]), fmaxf(red[2], red[3]));
  const float scale = fmaxf(m / 127.0f, 1e-8f);
  if (threadIdx.x == 0) scales[row] = scale;
  uint32_t* qr = (uint32_t*)(q + (size_t)row * K_DIM);
#pragma unroll
  for (int i = 0; i < 4; ++i) {
    const float4 t = v[i];
    const int a0 = (int)fminf(fmaxf(rintf(t.x / scale), -128.0f), 127.0f);
    const int a1 = (int)fminf(fmaxf(rintf(t.y / scale), -128.0f), 127.0f);
    const int a2 = (int)fminf(fmaxf(rintf(t.z / scale), -128.0f), 127.0f);
    const int a3 = (int)fminf(fmaxf(rintf(t.w / scale), -128.0f), 127.0f);
    const uint32_t p = (uint32_t)(a0 & 255) | ((uint32_t)(a1 & 255) << 8) |
                       ((uint32_t)(a2 & 255) << 16) | ((uint32_t)(a3 & 255) << 24);
    qr[threadIdx.x + i * TPB_Q] = p;
  }
}

// -------- 256x256 i8 GEMM, BK=64 ring-4 LDS, cross-barrier pre-read --------
// 8 waves (wm 2 x wn 4), per-wave C 128x64 = acc[8][4] (128 AGPRs);
// fragments a[8]+b[4] = 48 arch VGPRs, loop-carried. launch_bounds(512,2)
// (R11 lesson: (512,4) halves the unified reg budget below acc alone).
// LDS: per operand ring of 4 tiles (4 x 16 KiB x 2 = 128 KiB), rows 64 B =
// 4 chunks, swizzle phys_chunk = logical ^ ((row>>1)&3) (2-way = free).
// Steady tile T (1 barrier, no cold waits):
//   [b(T),a01(T) pre-read before last barrier]  -> GATE lgkm(6), MFMA mi01
//   a[2..7](T) issued post-barrier              -> GATE (4)/(2)/(0), mi23/45/67
//   stage(T+3) -> ring[(T+3)&3] (4 loads); vmcnt(4) = only that stage in
//   flight (stages <=T+2 landed -- no drain stall); pre-read b,a01(T+1);
//   s_barrier.
// Invariants (R12 fix): PRE_READ(T+1) before the end-of-T barrier is safe
// iff ALL waves' stage(T+1) landed before the end-of-(T-1) barrier. Steady
// state: wave Y's vmcnt(4)@end-of-(T-1) leaves only stage(T+2) -> ok.
// T=0 needs the PROLOGUE wait to cover stage(1): prologue issues 12 loads
// (tiles 0..2 x 4), waits vmcnt(4) -> tiles 0 AND 1 landed (R12's bug:
// vmcnt(16) > 12 waited for nothing -> race on tile 0/1).
// WAR on ring[(T+3)&3]=ring[(T-1)&3]: all reads of T-1 gated lgkm(0)
// before T-1's end barrier. Tail (T+3>=NT): vmcnt(0).
// XCD swizzle: grid 32r x 16c; XCD k owns rows[8*(k>>1),+8) x cols[8*(k&1),+8).
__global__ __launch_bounds__(512, 2) void gemm_i8_kernel(
    const signed char* __restrict__ qA, const signed char* __restrict__ qB,
    const float* __restrict__ sA, const float* __restrict__ sB,
    float* __restrict__ C, int M, int N, int K) {
  __shared__ __align__(16) signed char As[4 * TILE_BYTES];  // 64 KiB
  __shared__ __align__(16) signed char Bs[4 * TILE_BYTES];  // 64 KiB

  const int tid = threadIdx.x;
  const int wave = tid >> 6, lane = tid & 63;
  const int l16 = lane & 15, lhi = lane >> 4;
  const int wm = wave >> 2, wn = wave & 3;

  // XCD-chunked 2-D swizzle (bijective; 512 blocks, 8 XCDs, o%8 = XCD)
  const int o = blockIdx.x + blockIdx.y * gridDim.x;
  const int xcd = o & 7, slot = o >> 3;
  const int rb = ((xcd >> 1) << 3) + (slot >> 3);  // grid row 0..31
  const int cb = ((xcd & 1) << 3) + (slot & 7);    // grid col 0..15
  const int m0 = rb * BM, n0 = cb * BN;

  const signed char* Abase = qA + (size_t)m0 * K;
  const signed char* Bbase = qB + (size_t)n0 * K;

  // staging: tile = 1024 x 16B chunks; thread d = s*512+tid, s=0..1.
  // dest linear (wave-uniform base + lane*16); source inverse-swizzled.
  int soff[2], sdst[2];
#pragma unroll
  for (int s = 0; s < 2; ++s) {
    const int d = s * 512 + tid;
    const int r = d >> 2;                       // row 0..255 (4 chunks/row)
    const int c = (d & 3) ^ ((r >> 1) & 3);     // logical chunk at phys (d&3)
    soff[s] = r * K + c * 16;
    sdst[s] = s * 8192 + wave * 1024;
  }

#define STAGE_A(T_)                                                         \
  do {                                                                      \
    _Pragma("unroll") for (int s = 0; s < 2; ++s)                           \
        load_lds16(Abase + (size_t)(T_)*BKB + soff[s],                      \
                   As + ((T_)&3) * TILE_BYTES + sdst[s]);                   \
  } while (0)
#define STAGE_B(T_)                                                         \
  do {                                                                      \
    _Pragma("unroll") for (int s = 0; s < 2; ++s)                           \
        load_lds16(Bbase + (size_t)(T_)*BKB + soff[s],                      \
                   Bs + ((T_)&3) * TILE_BYTES + sdst[s]);                   \
  } while (0)

  // fragment reads: phys k-chunk = lhi ^ ((l16>>1)&3) (row multiples of 16
  // drop out of (row>>1)&3)
  const int axor = ((lhi ^ ((l16 >> 1) & 3)) << 4);
  const int aoff = wm * 8192 + l16 * 64;  // + mi*1024
  const int boff = wn * 4096 + l16 * 64;  // + nj*1024

  const v4i vz = {0, 0, 0, 0};
  v4i acc[8][4];
#pragma unroll
  for (int i = 0; i < 8; ++i)
#pragma unroll
    for (int j = 0; j < 4; ++j) acc[i][j] = vz;

  v4i a[8], b[4];  // loop-carried: b,a0,a1 pre-read across the barrier

#define PRE_READ(T_)                                                         \
  do {                                                                       \
    const signed char* Ap_ = As + ((T_)&3) * TILE_BYTES;                     \
    const signed char* Bp_ = Bs + ((T_)&3) * TILE_BYTES;                     \
    _Pragma("unroll") for (int nj = 0; nj < 4; ++nj)                         \
        b[nj] = *(const v4i*)(Bp_ + boff + nj * 1024 + axor);                \
    a[0] = *(const v4i*)(Ap_ + aoff + 0 * 1024 + axor);                     \
    a[1] = *(const v4i*)(Ap_ + aoff + 1 * 1024 + axor);                     \
  } while (0)

#define MFMA_PAIR(p0_, p1_)                                                  \
  do {                                                                       \
    _Pragma("unroll") for (int nj = 0; nj < 4; ++nj)                         \
        acc[p0_][nj] = __builtin_amdgcn_mfma_i32_16x16x64_i8(                \
            a[p0_], b[nj], acc[p0_][nj], 0, 0, 0);                           \
    _Pragma("unroll") for (int nj = 0; nj < 4; ++nj)                         \
        acc[p1_][nj] = __builtin_amdgcn_mfma_i32_16x16x64_i8(                \
            a[p1_], b[nj], acc[p1_][nj], 0, 0, 0);                           \
  } while (0)

#define LGKM_GATE(n_)                                       \
  do {                                                      \
    asm volatile("s_waitcnt lgkmcnt(" #n_ ")" ::: "memory");\
    __builtin_amdgcn_sched_barrier(0);                      \
  } while (0)

  // prologue: stage tiles 0..2 (12 loads); wait vmcnt(4) -> tiles 0 AND 1
  // landed (only stage(2)'s 4 loads outstanding); barrier; pre-read tile 0.
  STAGE_A(0); STAGE_B(0); STAGE_A(1); STAGE_B(1); STAGE_A(2); STAGE_B(2);
  asm volatile("s_waitcnt vmcnt(4)" ::: "memory");
  __builtin_amdgcn_s_barrier();
  PRE_READ(0);
  __builtin_amdgcn_sched_barrier(0);

  for (int T = 0; T < NT; ++T) {
    const signed char* Ar = As + (T & 3) * TILE_BYTES;

    // issue a[2..7] (post-barrier; covered by cluster-0's MFMA)
    a[2] = *(const v4i*)(Ar + aoff + 2 * 1024 + axor);
    a[3] = *(const v4i*)(Ar + aoff + 3 * 1024 + axor);
    __builtin_amdgcn_sched_barrier(0);
    a[4] = *(const v4i*)(Ar + aoff + 4 * 1024 + axor);
    a[5] = *(const v4i*)(Ar + aoff + 5 * 1024 + axor);
    __builtin_amdgcn_sched_barrier(0);
    a[6] = *(const v4i*)(Ar + aoff + 6 * 1024 + axor);
    a[7] = *(const v4i*)(Ar + aoff + 7 * 1024 + axor);
    __builtin_amdgcn_sched_barrier(0);

    // MFMA clusters; gates count: 6 pre-reads (done by barrier wait) + 6 new
    LGKM_GATE(6);
    __builtin_amdgcn_s_setprio(1);
    MFMA_PAIR(0, 1);
    __builtin_amdgcn_s_setprio(0);
    LGKM_GATE(4);
    __builtin_amdgcn_s_setprio(1);
    MFMA_PAIR(2, 3);
    __builtin_amdgcn_s_setprio(0);
    LGKM_GATE(2);
    __builtin_amdgcn_s_setprio(1);
    MFMA_PAIR(4, 5);
    __builtin_amdgcn_s_setprio(0);
    LGKM_GATE(0);
    __builtin_amdgcn_s_setprio(1);
    MFMA_PAIR(6, 7);
    __builtin_amdgcn_s_setprio(0);

    // stage 3 tiles ahead; boundary wait leaves only that stage in flight
    if (T + 3 < NT) {
      STAGE_A(T + 3); STAGE_B(T + 3);
      asm volatile("s_waitcnt vmcnt(4)" ::: "memory");
    } else {
      asm volatile("s_waitcnt vmcnt(0)" ::: "memory");
    }
    // pre-read next tile's b,a01 (buffer landed >=2 barriers ago, all waves)
    if (T + 1 < NT) {
      PRE_READ(T + 1);
      __builtin_amdgcn_sched_barrier(0);
    }
    __builtin_amdgcn_s_barrier();
  }

  // epilogue: C/D layout col = lane&15, row = (lane>>4)*4 + reg
  float sbv[4];
#pragma unroll
  for (int nj = 0; nj < 4; ++nj) sbv[nj] = sB[n0 + wn * 64 + nj * 16 + l16];
#pragma unroll
  for (int mi = 0; mi < 8; ++mi) {
#pragma unroll
    for (int r = 0; r < 4; ++r) {
      const int row = m0 + wm * 128 + mi * 16 + lhi * 4 + r;
      const float sav = sA[row];
      float* crow = C + (size_t)row * N + (n0 + wn * 64 + l16);
#pragma unroll
      for (int nj = 0; nj < 4; ++nj)
        crow[nj * 16] = (float)acc[mi][nj][r] * sav * sbv[nj];
    }
  }
}

extern "C" void kernel_launch(void* const* d_in, const int* in_sizes, int n_in,
                              void* d_out, int out_size, void* d_ws, size_t ws_size,
                              hipStream_t stream) {
  const float* A = (const float*)d_in[0];
  const float* B = (const float*)d_in[1];
  float* C = (float*)d_out;
  const int K = K_DIM;
  const int M = in_sizes[0] / K;  // 8192
  const int N = in_sizes[1] / K;  // 4096

  signed char* qA = (signed char*)d_ws;
  signed char* qB = qA + (size_t)M * K;
  float* sA = (float*)(qB + (size_t)N * K);
  float* sB = sA + M;

  quant_rows_kernel<<<M, TPB_Q, 0, stream>>>(A, qA, sA);
  quant_rows_kernel<<<N, TPB_Q, 0, stream>>>(B, qB, sB);

  dim3 grid(N / BN, M / BM);
  gemm_i8_kernel<<<grid, 512, 0, stream>>>(qA, qB, sA, sB, C, M, N, K);
}